// Round 2
// baseline (3202.078 us; speedup 1.0000x reference)
//
#include <hip/hip_runtime.h>
#include <math.h>

#define H_ 256
#define W_ 320
#define C_ 28
#define HWC (H_ * W_ * C_)          // 2293760 elems per batch
#define PI_D 3.14159265358979323846

__device__ __forceinline__ float gelu_f(float x) {
    return 0.5f * x * (1.0f + erff(x * 0.7071067811865476f));
}

// ---------------------------------------------------------------------------
// DCT basis matrices + analytic inverse (torch_dct DCT-II, norm=None)
// ---------------------------------------------------------------------------
__global__ void gen_mats(float* __restrict__ dh, float* __restrict__ dw,
                         float* __restrict__ dih, float* __restrict__ diw) {
    int i = blockIdx.x * 256 + threadIdx.x;
    if (i < 256 * 256) {
        int k = i >> 8, n = i & 255;
        double c = cos(PI_D * (2.0 * n + 1.0) * k / 512.0);
        dh[k * 256 + n] = (float)(2.0 * c);
        dih[n * 256 + k] = (float)(k == 0 ? (1.0 / 512.0) : c / 256.0);
    }
    if (i < 320 * 320) {
        int k = i / 320, n = i - k * 320;
        double c = cos(PI_D * (2.0 * n + 1.0) * k / 640.0);
        dw[k * 320 + n] = (float)(2.0 * c);
        diw[n * 320 + k] = (float)(k == 0 ? (1.0 / 640.0) : c / 320.0);
    }
}

// G[h][c][c'] = sum_d wq[c, h*28+d] * wkv[c', h*28+d] * 28^-0.5   (local attn)
__global__ void gen_locG(const float* __restrict__ wq, const float* __restrict__ wkv,
                         float* __restrict__ G) {
    int i = blockIdx.x * 256 + threadIdx.x;  // 8*28*28 = 6272
    if (i < 6272) {
        int h = i / 784, r = i - h * 784;
        int c = r / 28, cp = r - c * 28;
        float s = 0.f;
        #pragma unroll
        for (int d = 0; d < 28; ++d)
            s += wq[c * 224 + h * 28 + d] * wkv[cp * 448 + h * 28 + d];
        G[i] = s * 0.18898223650461363f;  // 28^-0.5
    }
}

// posT[h][j][i] = pos[h][i][j]   (so the i=lane index coalesces)
__global__ void gen_posT(const float* __restrict__ pos, float* __restrict__ posT) {
    int id = blockIdx.x * 256 + threadIdx.x;   // 32768
    int h = id >> 12, r = id & 4095, i = r >> 6, j = r & 63;
    posT[(h << 12) + (j << 6) + i] = pos[id];
}

// ---------------------------------------------------------------------------
// Generic strided matrix apply: out[m, c] = sum_k mat[m,k] * in[k, c]  (c=28)
// ---------------------------------------------------------------------------
__global__ void dct_apply(const float* __restrict__ mat, const float* __restrict__ in,
                          float* __restrict__ out, int M, int Kd, int inner_n,
                          int stride_i_in, int kstride_in,
                          int stride_i_out, int mstride_out) {
    extern __shared__ float s_in[];  // [Kd][28]
    int bidx = blockIdx.x;
    int o = bidx / inner_n;
    int ii = bidx - o * inner_n;
    const float* bin = in + (size_t)o * HWC + (size_t)ii * stride_i_in;
    float* bout = out + (size_t)o * HWC + (size_t)ii * stride_i_out;
    int tot = Kd * C_;
    for (int e = threadIdx.x; e < tot; e += blockDim.x) {
        int k = e / C_;
        int c = e - k * C_;
        s_in[e] = bin[k * kstride_in + c];
    }
    __syncthreads();
    int m = threadIdx.x;
    if (m < M) {
        float4 acc[7];
        #pragma unroll
        for (int q = 0; q < 7; ++q) acc[q] = make_float4(0.f, 0.f, 0.f, 0.f);
        const float* mr = mat + (size_t)m * Kd;
        for (int k = 0; k < Kd; ++k) {
            float d = mr[k];
            const float4* row = (const float4*)(s_in + k * C_);
            #pragma unroll
            for (int q = 0; q < 7; ++q) {
                float4 v = row[q];
                acc[q].x += d * v.x; acc[q].y += d * v.y;
                acc[q].z += d * v.z; acc[q].w += d * v.w;
            }
        }
        float4* orow = (float4*)(bout + (size_t)m * mstride_out);
        #pragma unroll
        for (int q = 0; q < 7; ++q) orow[q] = acc[q];
    }
}

// ---------------------------------------------------------------------------
// Spectral DCT-domain attention: ONE WAVE per (batch, 8x8 DCT patch).
// lane = m (0..63, patch position). Weights read via wave-uniform (scalar)
// loads; only Q,K (transposed access) and the 28x28 score live in LDS.
// ---------------------------------------------------------------------------
__global__ __launch_bounds__(64) void spec_attn(
    const float* __restrict__ xdct, const float* __restrict__ wq,
    const float* __restrict__ wk, const float* __restrict__ wv,
    const float* __restrict__ rescale, const float* __restrict__ pw,
    const float* __restrict__ pb, float* __restrict__ xlow) {
    __shared__ float s_q[64 * 28];
    __shared__ float s_k[64 * 28];
    __shared__ float s_att[28 * 29];
    __shared__ float s_qn[28];
    __shared__ float s_kn[28];
    int lane = threadIdx.x;
    int blk = blockIdx.x;
    int b = blk / 1280;
    int r = blk - b * 1280;
    int bh = r / 40;
    int bw = r - bh * 40;
    int kp = lane >> 3, lp = lane & 7;
    const float* rowp = xdct + ((size_t)((b * 256 + bh * 8 + kp) * 320) + bw * 8 + lp) * 28;
    float xt[28];
    #pragma unroll
    for (int q4 = 0; q4 < 7; ++q4) {
        float4 v4 = ((const float4*)rowp)[q4];
        xt[4 * q4] = v4.x; xt[4 * q4 + 1] = v4.y; xt[4 * q4 + 2] = v4.z; xt[4 * q4 + 3] = v4.w;
    }
    float acc[28];
    #pragma unroll
    for (int c = 0; c < 28; ++c) acc[c] = 0.f;

    for (int h = 0; h < 8; ++h) {
        float resc = rescale[h];
        // ---- Q projection (weights wave-uniform -> scalar loads) ----
        {
            float tq[28];
            #pragma unroll
            for (int d = 0; d < 28; ++d) tq[d] = 0.f;
            #pragma unroll
            for (int c = 0; c < 28; ++c) {
                float xc = xt[c];
                const float* wrow = wq + c * 224 + h * 28;
                #pragma unroll
                for (int d = 0; d < 28; ++d) tq[d] += xc * wrow[d];
            }
            float4* dst = (float4*)(s_q + lane * 28);
            #pragma unroll
            for (int q4 = 0; q4 < 7; ++q4)
                dst[q4] = make_float4(tq[4 * q4], tq[4 * q4 + 1], tq[4 * q4 + 2], tq[4 * q4 + 3]);
        }
        // ---- K projection ----
        {
            float tk[28];
            #pragma unroll
            for (int d = 0; d < 28; ++d) tk[d] = 0.f;
            #pragma unroll
            for (int c = 0; c < 28; ++c) {
                float xc = xt[c];
                const float* wrow = wk + c * 224 + h * 28;
                #pragma unroll
                for (int d = 0; d < 28; ++d) tk[d] += xc * wrow[d];
            }
            float4* dst = (float4*)(s_k + lane * 28);
            #pragma unroll
            for (int q4 = 0; q4 < 7; ++q4)
                dst[q4] = make_float4(tk[4 * q4], tk[4 * q4 + 1], tk[4 * q4 + 2], tk[4 * q4 + 3]);
        }
        // ---- V projection (stays in registers: v[e] is exactly V[e][lane]) ----
        float vvv[28];
        #pragma unroll
        for (int d = 0; d < 28; ++d) vvv[d] = 0.f;
        #pragma unroll
        for (int c = 0; c < 28; ++c) {
            float xc = xt[c];
            const float* wrow = wv + c * 224 + h * 28;
            #pragma unroll
            for (int d = 0; d < 28; ++d) vvv[d] += xc * wrow[d];
        }
        __syncthreads();
        // ---- column L2 norms over m (lanes 0..27 -> q, 32..59 -> k) ----
        if (lane < 28) {
            float s = 0.f;
            for (int m = 0; m < 64; ++m) { float t = s_q[m * 28 + lane]; s += t * t; }
            s_qn[lane] = fmaxf(sqrtf(s), 1e-12f);
        } else if (lane >= 32 && lane < 60) {
            int d = lane - 32;
            float s = 0.f;
            for (int m = 0; m < 64; ++m) { float t = s_k[m * 28 + d]; s += t * t; }
            s_kn[d] = fmaxf(sqrtf(s), 1e-12f);
        }
        __syncthreads();
        // ---- scores att[d][e] = resc * <q_d,k_e>/(|q_d||k_e|), 784 entries ----
        for (int it = 0; it < 13; ++it) {
            int id = it * 64 + lane;
            if (id < 784) {
                int d = id / 28, e = id - d * 28;
                float s = 0.f;
                #pragma unroll 4
                for (int m = 0; m < 64; ++m) s += s_q[m * 28 + d] * s_k[m * 28 + e];
                s_att[d * 29 + e] = s * resc / (s_qn[d] * s_kn[e]);
            }
        }
        __syncthreads();
        // ---- softmax over e (row d per lane, lanes 0..27) ----
        if (lane < 28) {
            float mx = -1e30f;
            #pragma unroll
            for (int e = 0; e < 28; ++e) mx = fmaxf(mx, s_att[lane * 29 + e]);
            float sum = 0.f;
            #pragma unroll
            for (int e = 0; e < 28; ++e) {
                float ex = __expf(s_att[lane * 29 + e] - mx);
                sum += ex; s_att[lane * 29 + e] = ex;
            }
            float inv = 1.0f / sum;
            #pragma unroll
            for (int e = 0; e < 28; ++e) s_att[lane * 29 + e] *= inv;
        }
        __syncthreads();
        // ---- x0[d][lane] = sum_e p[d][e]*v[e];  acc += x0 @ pw_h ----
        const float* pwh = pw + h * 28 * 28;
        for (int d = 0; d < 28; ++d) {
            float x0d = 0.f;
            const float* prow = s_att + d * 29;
            #pragma unroll
            for (int e = 0; e < 28; ++e) x0d += prow[e] * vvv[e];
            const float* pr = pwh + d * 28;
            #pragma unroll
            for (int co = 0; co < 28; ++co) acc[co] += x0d * pr[co];
        }
        __syncthreads();
    }
    float* op = xlow + ((size_t)((b * 256 + bh * 8 + kp) * 320) + bw * 8 + lp) * 28;
    float4* o4 = (float4*)op;
    #pragma unroll
    for (int q4 = 0; q4 < 7; ++q4)
        o4[q4] = make_float4(acc[4 * q4] + pb[4 * q4], acc[4 * q4 + 1] + pb[4 * q4 + 1],
                             acc[4 * q4 + 2] + pb[4 * q4 + 2], acc[4 * q4 + 3] + pb[4 * q4 + 3]);
}

// ---------------------------------------------------------------------------
// y1 = gelu(pointwise-conv(x_dct))
// ---------------------------------------------------------------------------
__global__ __launch_bounds__(256) void hf_pw1(const float* __restrict__ xdct,
                                              const float* __restrict__ w,
                                              float* __restrict__ y1) {
    __shared__ float s_w[28][29];
    __shared__ float s_x[256][29];
    int t = threadIdx.x;
    for (int e = t; e < 784; e += 256) s_w[e / 28][e % 28] = w[e];
    size_t p0 = (size_t)blockIdx.x * 256;
    const float* src = xdct + p0 * 28;
    for (int e = t; e < 7168; e += 256) {
        int p = e / 28, c = e - p * 28;
        s_x[p][c] = src[e];
    }
    __syncthreads();
    float o[28];
    #pragma unroll
    for (int oo = 0; oo < 28; ++oo) {
        float a = 0.f;
        #pragma unroll
        for (int c = 0; c < 28; ++c) a += s_w[oo][c] * s_x[t][c];
        o[oo] = gelu_f(a);
    }
    __syncthreads();
    #pragma unroll
    for (int oo = 0; oo < 28; ++oo) s_x[t][oo] = o[oo];
    __syncthreads();
    float* dst = y1 + p0 * 28;
    for (int e = t; e < 7168; e += 256) {
        int p = e / 28, c = e - p * 28;
        dst[e] = s_x[p][c];
    }
}

// ---------------------------------------------------------------------------
// Depthwise 3x3 + gelu + residual + pointwise2 + gelu + residual + coef blend
// ---------------------------------------------------------------------------
__global__ __launch_bounds__(256) void hf_combine(
    const float* __restrict__ y1, const float* __restrict__ xdct,
    const float* __restrict__ xlow, const float* __restrict__ dww,
    const float* __restrict__ pw2, const float* __restrict__ coef,
    float* __restrict__ xout) {
    __shared__ float s_dw[252];
    __shared__ float s_pw[28][29];
    int t = threadIdx.x;
    for (int e = t; e < 252; e += 256) s_dw[e] = dww[e];
    for (int e = t; e < 784; e += 256) s_pw[e / 28][e % 28] = pw2[e];
    __syncthreads();
    int pix = blockIdx.x * 256 + t;
    int b = pix / 81920;
    int rem = pix - b * 81920;
    int y = rem / 320;
    int xx = rem - y * 320;
    float conv[28];
    #pragma unroll
    for (int c = 0; c < 28; ++c) conv[c] = 0.f;
    for (int dy = 0; dy < 3; ++dy) {
        int yy = y + dy - 1;
        if (yy < 0 || yy >= 256) continue;
        for (int dx = 0; dx < 3; ++dx) {
            int xq = xx + dx - 1;
            if (xq < 0 || xq >= 320) continue;
            const float* rp = y1 + ((size_t)(b * 256 + yy) * 320 + xq) * 28;
            #pragma unroll
            for (int c = 0; c < 28; ++c) conv[c] += s_dw[c * 9 + dy * 3 + dx] * rp[c];
        }
    }
    const float* xd = xdct + (size_t)pix * 28;
    const float* xl = xlow + (size_t)pix * 28;
    float xdr[28], xcv[28];
    #pragma unroll
    for (int c = 0; c < 28; ++c) {
        xdr[c] = xd[c];
        xcv[c] = gelu_f(conv[c]) + xdr[c];
    }
    float cf = coef[rem];
    float omc = 1.0f - cf;
    float* xo = xout + (size_t)pix * 28;
    #pragma unroll
    for (int oo = 0; oo < 28; ++oo) {
        float a = 0.f;
        #pragma unroll
        for (int c = 0; c < 28; ++c) a += s_pw[oo][c] * xcv[c];
        float xh = gelu_f(a) + xcv[oo];
        xo[oo] = cf * xl[oo] + omc * xh + xdr[oo];
    }
}

// ---------------------------------------------------------------------------
// Windowed local attention: ONE WAVE per 8x8 window, loop over 8 heads.
// lane i owns window row i (its 28 input channels stay in registers).
// sim = (xw @ G) @ xw^T + pos via G = Wq Wk^T * 28^-0.5 (precomputed).
// Weight / other-row reads are wave-uniform -> scalar loads. LDS: V + P only.
// ---------------------------------------------------------------------------
__global__ __launch_bounds__(64) void local_attn(
    const float* __restrict__ x, const float* __restrict__ G,
    const float* __restrict__ wkv, const float* __restrict__ posT,
    const float* __restrict__ pw, const float* __restrict__ pb,
    float* __restrict__ outloc) {
    __shared__ float s_v[64 * 28];
    __shared__ float s_p[64 * 65];
    int lane = threadIdx.x;
    int blk = blockIdx.x;
    int b = blk / 1280;
    int r = blk - b * 1280;
    int wh = r / 40;
    int wwi = r - wh * 40;
    int p_ = lane >> 3, q_ = lane & 7;
    const float* rowp = x + ((size_t)((b * 256 + wh * 8 + p_) * 320) + wwi * 8 + q_) * 28;
    float xw[28];
    #pragma unroll
    for (int q4 = 0; q4 < 7; ++q4) {
        float4 v4 = ((const float4*)rowp)[q4];
        xw[4 * q4] = v4.x; xw[4 * q4 + 1] = v4.y; xw[4 * q4 + 2] = v4.z; xw[4 * q4 + 3] = v4.w;
    }
    float acc[28];
    #pragma unroll
    for (int c = 0; c < 28; ++c) acc[c] = 0.f;

    for (int h = 0; h < 8; ++h) {
        // ---- t1 = xw_row @ G_h  (G wave-uniform -> scalar loads) ----
        float t1[28];
        #pragma unroll
        for (int d = 0; d < 28; ++d) t1[d] = 0.f;
        const float* Gh = G + h * 784;
        #pragma unroll
        for (int c = 0; c < 28; ++c) {
            float xc = xw[c];
            const float* gr = Gh + c * 28;
            #pragma unroll
            for (int d = 0; d < 28; ++d) t1[d] += xc * gr[d];
        }
        // ---- V row = xw_row @ Wv_h -> LDS ----
        {
            float vv[28];
            #pragma unroll
            for (int d = 0; d < 28; ++d) vv[d] = 0.f;
            const float* wvh = wkv + 224 + h * 28;
            #pragma unroll
            for (int c = 0; c < 28; ++c) {
                float xc = xw[c];
                const float* wr = wvh + c * 448;
                #pragma unroll
                for (int d = 0; d < 28; ++d) vv[d] += xc * wr[d];
            }
            float4* dst = (float4*)(s_v + lane * 28);
            #pragma unroll
            for (int q4 = 0; q4 < 7; ++q4)
                dst[q4] = make_float4(vv[4 * q4], vv[4 * q4 + 1], vv[4 * q4 + 2], vv[4 * q4 + 3]);
        }
        __syncthreads();
        // ---- sim row: p[j] = <t1, xw_j> + pos[h][i][j]  (xw_j wave-uniform) ----
        const float* pT = posT + (h << 12);
        #pragma unroll 2
        for (int j = 0; j < 64; ++j) {
            const float* xj = x + ((size_t)((b * 256 + wh * 8 + (j >> 3)) * 320) + wwi * 8 + (j & 7)) * 28;
            float s = 0.f;
            #pragma unroll
            for (int c = 0; c < 28; ++c) s += t1[c] * xj[c];
            s_p[lane * 65 + j] = s + pT[(j << 6) + lane];
        }
        // ---- softmax over own row (lane-local) ----
        float mx = -1e30f;
        #pragma unroll 4
        for (int j = 0; j < 64; ++j) mx = fmaxf(mx, s_p[lane * 65 + j]);
        float sum = 0.f;
        #pragma unroll 4
        for (int j = 0; j < 64; ++j) {
            float ex = __expf(s_p[lane * 65 + j] - mx);
            sum += ex;
            s_p[lane * 65 + j] = ex;
        }
        float inv = 1.0f / sum;
        __syncthreads();
        // ---- PV: ol[d] = sum_j p[j] * V[j][d]  (V rows broadcast) ----
        float ol[28];
        #pragma unroll
        for (int d = 0; d < 28; ++d) ol[d] = 0.f;
        #pragma unroll 2
        for (int j = 0; j < 64; ++j) {
            float pj = s_p[lane * 65 + j];
            const float4* vr = (const float4*)(s_v + j * 28);
            #pragma unroll
            for (int q4 = 0; q4 < 7; ++q4) {
                float4 v4 = vr[q4];
                ol[4 * q4] += pj * v4.x; ol[4 * q4 + 1] += pj * v4.y;
                ol[4 * q4 + 2] += pj * v4.z; ol[4 * q4 + 3] += pj * v4.w;
            }
        }
        // ---- proj accumulate: acc[co] += (ol[d]*inv) * pw[h*28+d][co] ----
        const float* pwh = pw + (h * 28) * 28;
        #pragma unroll
        for (int d = 0; d < 28; ++d) {
            float od = ol[d] * inv;
            const float* pr = pwh + d * 28;
            #pragma unroll
            for (int co = 0; co < 28; ++co) acc[co] += od * pr[co];
        }
        __syncthreads();
    }
    float* op = outloc + ((size_t)((b * 256 + wh * 8 + p_) * 320) + wwi * 8 + q_) * 28;
    float4* o4 = (float4*)op;
    #pragma unroll
    for (int q4 = 0; q4 < 7; ++q4)
        o4[q4] = make_float4(acc[4 * q4] + pb[4 * q4], acc[4 * q4 + 1] + pb[4 * q4 + 1],
                             acc[4 * q4 + 2] + pb[4 * q4 + 2], acc[4 * q4 + 3] + pb[4 * q4 + 3]);
}

// ---------------------------------------------------------------------------
// Fusion: out = fus_w[:, :28] @ out_fd + fus_w[:, 28:] @ out_local + fus_b
// ---------------------------------------------------------------------------
__global__ __launch_bounds__(256) void fuse_k(
    const float* __restrict__ fd, const float* __restrict__ loc,
    const float* __restrict__ w, const float* __restrict__ bias,
    float* __restrict__ out) {
    __shared__ float s_w[28][57];
    __shared__ float s_b[28];
    int t = threadIdx.x;
    for (int e = t; e < 28 * 56; e += 256) s_w[e / 56][e % 56] = w[e];
    if (t < 28) s_b[t] = bias[t];
    __syncthreads();
    size_t pix = (size_t)blockIdx.x * 256 + t;
    const float* f = fd + pix * 28;
    const float* l = loc + pix * 28;
    float fr[28], lr[28];
    #pragma unroll
    for (int c = 0; c < 28; ++c) { fr[c] = f[c]; lr[c] = l[c]; }
    float* o = out + pix * 28;
    #pragma unroll
    for (int oo = 0; oo < 28; ++oo) {
        float a = s_b[oo];
        #pragma unroll
        for (int c = 0; c < 28; ++c) a += s_w[oo][c] * fr[c] + s_w[oo][28 + c] * lr[c];
        o[oo] = a;
    }
}

extern "C" void kernel_launch(void* const* d_in, const int* in_sizes, int n_in,
                              void* d_out, int out_size, void* d_ws, size_t ws_size,
                              hipStream_t stream) {
    const float* x         = (const float*)d_in[0];
    const float* spec_wq   = (const float*)d_in[1];
    const float* spec_wk   = (const float*)d_in[2];
    const float* spec_wv   = (const float*)d_in[3];
    const float* spec_resc = (const float*)d_in[4];
    const float* spec_pw   = (const float*)d_in[5];
    const float* spec_pb   = (const float*)d_in[6];
    const float* hf1_pw_w  = (const float*)d_in[7];
    const float* hf1_dw_w  = (const float*)d_in[8];
    const float* hf2_pw_w  = (const float*)d_in[9];
    const float* coef_emb  = (const float*)d_in[10];
    const float* loc_wq    = (const float*)d_in[11];
    const float* loc_wkv   = (const float*)d_in[12];
    const float* loc_pos   = (const float*)d_in[13];
    const float* loc_pw    = (const float*)d_in[14];
    const float* loc_pb    = (const float*)d_in[15];
    const float* fus_w     = (const float*)d_in[16];
    const float* fus_b     = (const float*)d_in[17];

    float* ws = (float*)d_ws;
    float* mDH  = ws;                       // 65536
    float* mDW  = mDH + 65536;              // 102400
    float* mDIH = mDW + 102400;             // 65536
    float* mDIW = mDIH + 65536;             // 102400
    float* locG = mDIW + 102400;            // 6272
    float* posT = locG + 6272;              // 32768
    float* bufA = posT + 32768;             // 2*HWC each
    float* bufB = bufA + 2 * HWC;
    float* bufC = bufB + 2 * HWC;
    float* bufD = bufC + 2 * HWC;

    gen_mats<<<400, 256, 0, stream>>>(mDH, mDW, mDIH, mDIW);
    gen_locG<<<25, 256, 0, stream>>>(loc_wq, loc_wkv, locG);
    gen_posT<<<128, 256, 0, stream>>>(loc_pos, posT);

    // forward DCT
    dct_apply<<<640, 256, 256 * 28 * 4, stream>>>(mDH, x, bufA,
        256, 256, 320, 28, 8960, 28, 8960);
    dct_apply<<<512, 320, 320 * 28 * 4, stream>>>(mDW, bufA, bufB,
        320, 320, 256, 8960, 28, 8960, 28);

    // spectral attention -> x_low (bufC)
    spec_attn<<<2560, 64, 0, stream>>>(bufB, spec_wq, spec_wk, spec_wv,
                                       spec_resc, spec_pw, spec_pb, bufC);
    // high-frequency path
    hf_pw1<<<640, 256, 0, stream>>>(bufB, hf1_pw_w, bufA);
    hf_combine<<<640, 256, 0, stream>>>(bufA, bufB, bufC, hf1_dw_w, hf2_pw_w,
                                        coef_emb, bufD);
    // inverse DCT: x_out (bufD) -> out_fd (bufC)
    dct_apply<<<640, 256, 256 * 28 * 4, stream>>>(mDIH, bufD, bufA,
        256, 256, 320, 28, 8960, 28, 8960);
    dct_apply<<<512, 320, 320 * 28 * 4, stream>>>(mDIW, bufA, bufC,
        320, 320, 256, 8960, 28, 8960, 28);

    // local windowed attention -> bufB
    local_attn<<<2560, 64, 0, stream>>>(x, locG, loc_wkv, posT,
                                        loc_pw, loc_pb, bufB);

    // fusion -> output
    fuse_k<<<640, 256, 0, stream>>>(bufC, bufB, fus_w, fus_b, (float*)d_out);
}

// Round 3
// 1786.444 us; speedup vs baseline: 1.7924x; 1.7924x over previous
//
#include <hip/hip_runtime.h>
#include <math.h>

#define H_ 256
#define W_ 320
#define C_ 28
#define HWC (H_ * W_ * C_)          // 2293760 elems per batch
#define PI_D 3.14159265358979323846

__device__ __forceinline__ float gelu_f(float x) {
    return 0.5f * x * (1.0f + erff(x * 0.7071067811865476f));
}

// ---------------------------------------------------------------------------
// DCT basis matrices, stored TRANSPOSED for coalesced per-lane access:
// dhT[n*256+k]  = 2*cos(pi*(2n+1)k/512)          (fwd H:  matT[kk*M + m], kk=n, m=k)
// dihT[k*256+n] = (k==0 ? 1/512 : cos(.)/256)    (inv H:  kk=k, m=n)
// ---------------------------------------------------------------------------
__global__ void gen_mats(float* __restrict__ dhT, float* __restrict__ dwT,
                         float* __restrict__ dihT, float* __restrict__ diwT) {
    int i = blockIdx.x * 256 + threadIdx.x;
    if (i < 256 * 256) {
        int k = i >> 8, n = i & 255;
        double c = cos(PI_D * (2.0 * n + 1.0) * k / 512.0);
        dhT[n * 256 + k] = (float)(2.0 * c);
        dihT[k * 256 + n] = (float)(k == 0 ? (1.0 / 512.0) : c / 256.0);
    }
    if (i < 320 * 320) {
        int k = i / 320, n = i - k * 320;
        double c = cos(PI_D * (2.0 * n + 1.0) * k / 640.0);
        dwT[n * 320 + k] = (float)(2.0 * c);
        diwT[k * 320 + n] = (float)(k == 0 ? (1.0 / 640.0) : c / 320.0);
    }
}

// G[h][c][c'] = sum_d wq[c, h*28+d] * wkv[c', h*28+d] * 28^-0.5   (local attn)
__global__ void gen_locG(const float* __restrict__ wq, const float* __restrict__ wkv,
                         float* __restrict__ G) {
    int i = blockIdx.x * 256 + threadIdx.x;  // 6272
    if (i < 6272) {
        int h = i / 784, r = i - h * 784;
        int c = r / 28, cp = r - c * 28;
        float s = 0.f;
        #pragma unroll
        for (int d = 0; d < 28; ++d)
            s += wq[c * 224 + h * 28 + d] * wkv[cp * 448 + h * 28 + d];
        G[i] = s * 0.18898223650461363f;  // 28^-0.5
    }
}

// M2[h][c][co] = sum_d Wv_h[c][d] * pw_h[d][co]   (fold V-proj into out-proj)
__global__ void gen_locM2(const float* __restrict__ wkv, const float* __restrict__ pw,
                          float* __restrict__ M2) {
    int i = blockIdx.x * 256 + threadIdx.x;  // 6272
    if (i < 6272) {
        int h = i / 784, r = i - h * 784;
        int c = r / 28, co = r - c * 28;
        float s = 0.f;
        #pragma unroll
        for (int d = 0; d < 28; ++d)
            s += wkv[c * 448 + 224 + h * 28 + d] * pw[(h * 28 + d) * 28 + co];
        M2[i] = s;
    }
}

// posT[h][j][i] = pos[h][i][j]   (so i = lane coalesces)
__global__ void gen_posT(const float* __restrict__ pos, float* __restrict__ posT) {
    int id = blockIdx.x * 256 + threadIdx.x;   // 32768
    int h = id >> 12, r = id & 4095, i = r >> 6, j = r & 63;
    posT[(h << 12) + (j << 6) + i] = pos[id];
}

// ---------------------------------------------------------------------------
// Strided matrix apply with TRANSPOSED matrix: out[m,c] = sum_k matT[k*M+m] in[k,c]
// ---------------------------------------------------------------------------
__global__ void dct_apply(const float* __restrict__ matT, const float* __restrict__ in,
                          float* __restrict__ out, int M, int Kd, int inner_n,
                          int stride_i_in, int kstride_in,
                          int stride_i_out, int mstride_out) {
    extern __shared__ float s_in[];  // [Kd][28]
    int bidx = blockIdx.x;
    int o = bidx / inner_n;
    int ii = bidx - o * inner_n;
    const float* bin = in + (size_t)o * HWC + (size_t)ii * stride_i_in;
    float* bout = out + (size_t)o * HWC + (size_t)ii * stride_i_out;
    int tot = Kd * C_;
    for (int e = threadIdx.x; e < tot; e += blockDim.x) {
        int k = e / C_;
        int c = e - k * C_;
        s_in[e] = bin[k * kstride_in + c];
    }
    __syncthreads();
    int m = threadIdx.x;
    if (m < M) {
        float4 acc[7];
        #pragma unroll
        for (int q = 0; q < 7; ++q) acc[q] = make_float4(0.f, 0.f, 0.f, 0.f);
        for (int k = 0; k < Kd; ++k) {
            float d = matT[k * M + m];   // coalesced across lanes
            const float4* row = (const float4*)(s_in + k * C_);
            #pragma unroll
            for (int q = 0; q < 7; ++q) {
                float4 v = row[q];
                acc[q].x += d * v.x; acc[q].y += d * v.y;
                acc[q].z += d * v.z; acc[q].w += d * v.w;
            }
        }
        float4* orow = (float4*)(bout + (size_t)m * mstride_out);
        #pragma unroll
        for (int q = 0; q < 7; ++q) orow[q] = acc[q];
    }
}

// ---------------------------------------------------------------------------
// Spectral DCT attention: one wave per (b, patch). M3-fold:
// out_m[co] += sum_e V[m][e] * M3[e][co],  M3 = P^T @ pw_h  (P normalized)
// ---------------------------------------------------------------------------
__global__ __launch_bounds__(64, 2) void spec_attn(
    const float* __restrict__ xdct, const float* __restrict__ wq,
    const float* __restrict__ wk, const float* __restrict__ wv,
    const float* __restrict__ rescale, const float* __restrict__ pw,
    const float* __restrict__ pb, float* __restrict__ xlow) {
    __shared__ float s_q[64 * 28];       // Q; reused for M3 [28*28]
    __shared__ float s_k[64 * 28];       // K; reused for pw_h staging
    __shared__ float s_att[28 * 29];
    __shared__ float s_qn[28];
    __shared__ float s_kn[28];
    int lane = threadIdx.x;
    int blk = blockIdx.x;
    int b = blk / 1280;
    int r = blk - b * 1280;
    int bh = r / 40;
    int bw = r - bh * 40;
    int kp = lane >> 3, lp = lane & 7;
    const float* rowp = xdct + ((size_t)((b * 256 + bh * 8 + kp) * 320) + bw * 8 + lp) * 28;
    float xt[28];
    #pragma unroll
    for (int q4 = 0; q4 < 7; ++q4) {
        float4 v4 = ((const float4*)rowp)[q4];
        xt[4 * q4] = v4.x; xt[4 * q4 + 1] = v4.y; xt[4 * q4 + 2] = v4.z; xt[4 * q4 + 3] = v4.w;
    }
    float acc[28];
    #pragma unroll
    for (int c = 0; c < 28; ++c) acc[c] = 0.f;

    for (int h = 0; h < 8; ++h) {
        float resc = rescale[h];
        // ---- Q,K,V projections (weights wave-uniform -> scalar loads) ----
        float tq[28], tk[28], vvv[28];
        #pragma unroll
        for (int d = 0; d < 28; ++d) { tq[d] = 0.f; tk[d] = 0.f; vvv[d] = 0.f; }
        #pragma unroll
        for (int c = 0; c < 28; ++c) {
            float xc = xt[c];
            const float* wqr = wq + c * 224 + h * 28;
            const float* wkr = wk + c * 224 + h * 28;
            const float* wvr = wv + c * 224 + h * 28;
            #pragma unroll
            for (int d = 0; d < 28; ++d) {
                tq[d] += xc * wqr[d];
                tk[d] += xc * wkr[d];
                vvv[d] += xc * wvr[d];
            }
        }
        {
            float4* dq = (float4*)(s_q + lane * 28);
            float4* dk = (float4*)(s_k + lane * 28);
            #pragma unroll
            for (int q4 = 0; q4 < 7; ++q4) {
                dq[q4] = make_float4(tq[4 * q4], tq[4 * q4 + 1], tq[4 * q4 + 2], tq[4 * q4 + 3]);
                dk[q4] = make_float4(tk[4 * q4], tk[4 * q4 + 1], tk[4 * q4 + 2], tk[4 * q4 + 3]);
            }
        }
        __syncthreads();
        // ---- column L2 norms over m (4-way partial chains) ----
        if (lane < 28) {
            float a0 = 0.f, a1 = 0.f, a2 = 0.f, a3 = 0.f;
            #pragma unroll 4
            for (int m = 0; m < 64; m += 4) {
                float t0 = s_q[m * 28 + lane], t1 = s_q[(m + 1) * 28 + lane];
                float t2 = s_q[(m + 2) * 28 + lane], t3 = s_q[(m + 3) * 28 + lane];
                a0 += t0 * t0; a1 += t1 * t1; a2 += t2 * t2; a3 += t3 * t3;
            }
            s_qn[lane] = fmaxf(sqrtf((a0 + a1) + (a2 + a3)), 1e-12f);
        } else if (lane >= 32 && lane < 60) {
            int d = lane - 32;
            float a0 = 0.f, a1 = 0.f, a2 = 0.f, a3 = 0.f;
            #pragma unroll 4
            for (int m = 0; m < 64; m += 4) {
                float t0 = s_k[m * 28 + d], t1 = s_k[(m + 1) * 28 + d];
                float t2 = s_k[(m + 2) * 28 + d], t3 = s_k[(m + 3) * 28 + d];
                a0 += t0 * t0; a1 += t1 * t1; a2 += t2 * t2; a3 += t3 * t3;
            }
            s_kn[d] = fmaxf(sqrtf((a0 + a1) + (a2 + a3)), 1e-12f);
        }
        __syncthreads();
        // ---- scores att[d][e] (784 entries over 13 iters, 4 partial chains) ----
        for (int it = 0; it < 13; ++it) {
            int id = it * 64 + lane;
            if (id < 784) {
                int d = id / 28, e = id - d * 28;
                float a0 = 0.f, a1 = 0.f, a2 = 0.f, a3 = 0.f;
                #pragma unroll 4
                for (int m = 0; m < 64; m += 4) {
                    a0 += s_q[m * 28 + d] * s_k[m * 28 + e];
                    a1 += s_q[(m + 1) * 28 + d] * s_k[(m + 1) * 28 + e];
                    a2 += s_q[(m + 2) * 28 + d] * s_k[(m + 2) * 28 + e];
                    a3 += s_q[(m + 3) * 28 + d] * s_k[(m + 3) * 28 + e];
                }
                s_att[d * 29 + e] = ((a0 + a1) + (a2 + a3)) * resc / (s_qn[d] * s_kn[e]);
            }
        }
        __syncthreads();
        // ---- stage pw_h into s_k (K is dead); softmax rows (no max-sub, |s|<=1) ----
        for (int it = 0; it < 13; ++it) {
            int id = it * 64 + lane;
            if (id < 784) s_k[id] = pw[h * 784 + id];
        }
        if (lane < 28) {
            float sum = 0.f;
            #pragma unroll
            for (int e = 0; e < 28; ++e) {
                float ex = __expf(s_att[lane * 29 + e]);
                s_att[lane * 29 + e] = ex; sum += ex;
            }
            float inv = 1.0f / sum;
            #pragma unroll
            for (int e = 0; e < 28; ++e) s_att[lane * 29 + e] *= inv;
        }
        __syncthreads();
        // ---- M3[e][co] = sum_d P[d][e]*pw_h[d][co] -> reuse s_q ----
        for (int it = 0; it < 13; ++it) {
            int id = it * 64 + lane;
            if (id < 784) {
                int e = id / 28, co = id - e * 28;
                float a0 = 0.f, a1 = 0.f;
                #pragma unroll 2
                for (int d = 0; d < 28; d += 2) {
                    a0 += s_att[d * 29 + e] * s_k[d * 28 + co];
                    a1 += s_att[(d + 1) * 29 + e] * s_k[(d + 1) * 28 + co];
                }
                s_q[e * 28 + co] = a0 + a1;
            }
        }
        __syncthreads();
        // ---- acc[co] += sum_e V[m][e] * M3[e][co]  (rows broadcast) ----
        #pragma unroll 4
        for (int e = 0; e < 28; ++e) {
            float ve = vvv[e];
            const float4* mr = (const float4*)(s_q + e * 28);
            #pragma unroll
            for (int q4 = 0; q4 < 7; ++q4) {
                float4 v4 = mr[q4];
                acc[4 * q4] += ve * v4.x; acc[4 * q4 + 1] += ve * v4.y;
                acc[4 * q4 + 2] += ve * v4.z; acc[4 * q4 + 3] += ve * v4.w;
            }
        }
        __syncthreads();   // protect s_q/s_k before next head's stores
    }
    float* op = xlow + ((size_t)((b * 256 + bh * 8 + kp) * 320) + bw * 8 + lp) * 28;
    float4* o4 = (float4*)op;
    #pragma unroll
    for (int q4 = 0; q4 < 7; ++q4)
        o4[q4] = make_float4(acc[4 * q4] + pb[4 * q4], acc[4 * q4 + 1] + pb[4 * q4 + 1],
                             acc[4 * q4 + 2] + pb[4 * q4 + 2], acc[4 * q4 + 3] + pb[4 * q4 + 3]);
}

// ---------------------------------------------------------------------------
// y1 = gelu(pointwise-conv(x_dct))
// ---------------------------------------------------------------------------
__global__ __launch_bounds__(256) void hf_pw1(const float* __restrict__ xdct,
                                              const float* __restrict__ w,
                                              float* __restrict__ y1) {
    __shared__ float s_w[28][29];
    __shared__ float s_x[256][29];
    int t = threadIdx.x;
    for (int e = t; e < 784; e += 256) s_w[e / 28][e % 28] = w[e];
    size_t p0 = (size_t)blockIdx.x * 256;
    const float* src = xdct + p0 * 28;
    for (int e = t; e < 7168; e += 256) {
        int p = e / 28, c = e - p * 28;
        s_x[p][c] = src[e];
    }
    __syncthreads();
    float o[28];
    #pragma unroll
    for (int oo = 0; oo < 28; ++oo) {
        float a = 0.f;
        #pragma unroll
        for (int c = 0; c < 28; ++c) a += s_w[oo][c] * s_x[t][c];
        o[oo] = gelu_f(a);
    }
    __syncthreads();
    #pragma unroll
    for (int oo = 0; oo < 28; ++oo) s_x[t][oo] = o[oo];
    __syncthreads();
    float* dst = y1 + p0 * 28;
    for (int e = t; e < 7168; e += 256) {
        int p = e / 28, c = e - p * 28;
        dst[e] = s_x[p][c];
    }
}

// ---------------------------------------------------------------------------
// Depthwise 3x3 + gelu + residual + pointwise2 + gelu + residual + coef blend
// ---------------------------------------------------------------------------
__global__ __launch_bounds__(256) void hf_combine(
    const float* __restrict__ y1, const float* __restrict__ xdct,
    const float* __restrict__ xlow, const float* __restrict__ dww,
    const float* __restrict__ pw2, const float* __restrict__ coef,
    float* __restrict__ xout) {
    __shared__ float s_dw[252];
    __shared__ float s_pw[28][29];
    int t = threadIdx.x;
    for (int e = t; e < 252; e += 256) s_dw[e] = dww[e];
    for (int e = t; e < 784; e += 256) s_pw[e / 28][e % 28] = pw2[e];
    __syncthreads();
    int pix = blockIdx.x * 256 + t;
    int b = pix / 81920;
    int rem = pix - b * 81920;
    int y = rem / 320;
    int xx = rem - y * 320;
    float conv[28];
    #pragma unroll
    for (int c = 0; c < 28; ++c) conv[c] = 0.f;
    for (int dy = 0; dy < 3; ++dy) {
        int yy = y + dy - 1;
        if (yy < 0 || yy >= 256) continue;
        for (int dx = 0; dx < 3; ++dx) {
            int xq = xx + dx - 1;
            if (xq < 0 || xq >= 320) continue;
            const float* rp = y1 + ((size_t)(b * 256 + yy) * 320 + xq) * 28;
            #pragma unroll
            for (int c = 0; c < 28; ++c) conv[c] += s_dw[c * 9 + dy * 3 + dx] * rp[c];
        }
    }
    const float* xd = xdct + (size_t)pix * 28;
    const float* xl = xlow + (size_t)pix * 28;
    float xdr[28], xcv[28];
    #pragma unroll
    for (int c = 0; c < 28; ++c) {
        xdr[c] = xd[c];
        xcv[c] = gelu_f(conv[c]) + xdr[c];
    }
    float cf = coef[rem];
    float omc = 1.0f - cf;
    float* xo = xout + (size_t)pix * 28;
    #pragma unroll
    for (int oo = 0; oo < 28; ++oo) {
        float a = 0.f;
        #pragma unroll
        for (int c = 0; c < 28; ++c) a += s_pw[oo][c] * xcv[c];
        float xh = gelu_f(a) + xcv[oo];
        xo[oo] = cf * xl[oo] + omc * xh + xdr[oo];
    }
}

// ---------------------------------------------------------------------------
// Local windowed attention v3: 256 threads = 4 waves = 4 windows.
// All-head G/M2 staged in LDS once; Xw rows staged per wave; ONE barrier.
// Per head: t1 = xw@G_h; single-pass no-max softmax accumulating
// u = sum_j exp(s_j)*xw_j; acc += (u/S) @ M2_h.
// ---------------------------------------------------------------------------
__global__ __launch_bounds__(256, 2) void local_attn(
    const float* __restrict__ x, const float* __restrict__ G,
    const float* __restrict__ M2, const float* __restrict__ posT,
    const float* __restrict__ pb, float* __restrict__ outloc) {
    __shared__ float s_G[8 * 784];     // 25088 B
    __shared__ float s_M2[8 * 784];    // 25088 B
    __shared__ float s_xw[4 * 64 * 28]; // 28672 B
    int t = threadIdx.x;
    int wave = t >> 6, lane = t & 63;
    for (int e = t; e < 6272; e += 256) { s_G[e] = G[e]; s_M2[e] = M2[e]; }
    int win = blockIdx.x * 4 + wave;
    int b = win / 1280;
    int r = win - b * 1280;
    int wh = r / 40, wwi = r - wh * 40;
    int p_ = lane >> 3, q_ = lane & 7;
    const float* rowp = x + ((size_t)((b * 256 + wh * 8 + p_) * 320) + wwi * 8 + q_) * 28;
    float xw[28];
    float* sxw_mine = s_xw + (wave * 64 + lane) * 28;
    #pragma unroll
    for (int q4 = 0; q4 < 7; ++q4) {
        float4 v4 = ((const float4*)rowp)[q4];
        xw[4 * q4] = v4.x; xw[4 * q4 + 1] = v4.y; xw[4 * q4 + 2] = v4.z; xw[4 * q4 + 3] = v4.w;
        ((float4*)sxw_mine)[q4] = v4;
    }
    __syncthreads();   // the only barrier
    float acc[28];
    #pragma unroll
    for (int c = 0; c < 28; ++c) acc[c] = 0.f;
    const float* swbase = s_xw + wave * 1792;
    for (int h = 0; h < 8; ++h) {
        // ---- t1 = xw @ G_h (G rows broadcast from LDS) ----
        float t1[28];
        #pragma unroll
        for (int d = 0; d < 28; ++d) t1[d] = 0.f;
        const float* gh = s_G + h * 784;
        #pragma unroll
        for (int c = 0; c < 28; ++c) {
            float xc = xw[c];
            const float* gr = gh + c * 28;
            #pragma unroll
            for (int d = 0; d < 28; ++d) t1[d] += xc * gr[d];
        }
        // ---- single-pass: s_j, p=exp(s_j), S += p, u += p * xw_j ----
        float S = 0.f;
        float u[28];
        #pragma unroll
        for (int c = 0; c < 28; ++c) u[c] = 0.f;
        const float* pbase = posT + (h << 12) + lane;
        for (int j = 0; j < 64; ++j) {
            const float4* rj = (const float4*)(swbase + j * 28);
            float rr[28];
            #pragma unroll
            for (int q4 = 0; q4 < 7; ++q4) {
                float4 v4 = rj[q4];
                rr[4 * q4] = v4.x; rr[4 * q4 + 1] = v4.y;
                rr[4 * q4 + 2] = v4.z; rr[4 * q4 + 3] = v4.w;
            }
            float a0 = 0.f, a1 = 0.f, a2 = 0.f, a3 = 0.f;
            #pragma unroll
            for (int c = 0; c < 28; c += 4) {
                a0 += t1[c] * rr[c];
                a1 += t1[c + 1] * rr[c + 1];
                a2 += t1[c + 2] * rr[c + 2];
                a3 += t1[c + 3] * rr[c + 3];
            }
            float s = ((a0 + a1) + (a2 + a3)) + pbase[j << 6];
            float p = __expf(s);
            S += p;
            #pragma unroll
            for (int c = 0; c < 28; ++c) u[c] += p * rr[c];
        }
        float inv = 1.0f / S;
        // ---- acc += (u*inv) @ M2_h ----
        const float* mh = s_M2 + h * 784;
        #pragma unroll
        for (int c = 0; c < 28; ++c) {
            float uc = u[c] * inv;
            const float* mr = mh + c * 28;
            #pragma unroll
            for (int co = 0; co < 28; ++co) acc[co] += uc * mr[co];
        }
    }
    float* op = outloc + ((size_t)((b * 256 + wh * 8 + p_) * 320) + wwi * 8 + q_) * 28;
    #pragma unroll
    for (int q4 = 0; q4 < 7; ++q4) {
        float4 o4;
        o4.x = acc[4 * q4] + pb[4 * q4];
        o4.y = acc[4 * q4 + 1] + pb[4 * q4 + 1];
        o4.z = acc[4 * q4 + 2] + pb[4 * q4 + 2];
        o4.w = acc[4 * q4 + 3] + pb[4 * q4 + 3];
        ((float4*)op)[q4] = o4;
    }
}

// ---------------------------------------------------------------------------
// Fusion: out = fus_w[:, :28] @ out_fd + fus_w[:, 28:] @ out_local + fus_b
// ---------------------------------------------------------------------------
__global__ __launch_bounds__(256) void fuse_k(
    const float* __restrict__ fd, const float* __restrict__ loc,
    const float* __restrict__ w, const float* __restrict__ bias,
    float* __restrict__ out) {
    __shared__ float s_w[28][57];
    __shared__ float s_b[28];
    int t = threadIdx.x;
    for (int e = t; e < 28 * 56; e += 256) s_w[e / 56][e % 56] = w[e];
    if (t < 28) s_b[t] = bias[t];
    __syncthreads();
    size_t pix = (size_t)blockIdx.x * 256 + t;
    const float* f = fd + pix * 28;
    const float* l = loc + pix * 28;
    float fr[28], lr[28];
    #pragma unroll
    for (int c = 0; c < 28; ++c) { fr[c] = f[c]; lr[c] = l[c]; }
    float* o = out + pix * 28;
    #pragma unroll
    for (int oo = 0; oo < 28; ++oo) {
        float a = s_b[oo];
        #pragma unroll
        for (int c = 0; c < 28; ++c) a += s_w[oo][c] * fr[c] + s_w[oo][28 + c] * lr[c];
        o[oo] = a;
    }
}

extern "C" void kernel_launch(void* const* d_in, const int* in_sizes, int n_in,
                              void* d_out, int out_size, void* d_ws, size_t ws_size,
                              hipStream_t stream) {
    const float* x         = (const float*)d_in[0];
    const float* spec_wq   = (const float*)d_in[1];
    const float* spec_wk   = (const float*)d_in[2];
    const float* spec_wv   = (const float*)d_in[3];
    const float* spec_resc = (const float*)d_in[4];
    const float* spec_pw   = (const float*)d_in[5];
    const float* spec_pb   = (const float*)d_in[6];
    const float* hf1_pw_w  = (const float*)d_in[7];
    const float* hf1_dw_w  = (const float*)d_in[8];
    const float* hf2_pw_w  = (const float*)d_in[9];
    const float* coef_emb  = (const float*)d_in[10];
    const float* loc_wq    = (const float*)d_in[11];
    const float* loc_wkv   = (const float*)d_in[12];
    const float* loc_pos   = (const float*)d_in[13];
    const float* loc_pw    = (const float*)d_in[14];
    const float* loc_pb    = (const float*)d_in[15];
    const float* fus_w     = (const float*)d_in[16];
    const float* fus_b     = (const float*)d_in[17];

    float* ws = (float*)d_ws;
    float* mDH  = ws;                       // 65536
    float* mDW  = mDH + 65536;              // 102400
    float* mDIH = mDW + 102400;             // 65536
    float* mDIW = mDIH + 65536;             // 102400
    float* locG = mDIW + 102400;            // 6272
    float* locM2 = locG + 6272;             // 6272
    float* posT = locM2 + 6272;             // 32768
    float* bufA = posT + 32768;             // 2*HWC each
    float* bufB = bufA + 2 * HWC;
    float* bufC = bufB + 2 * HWC;
    float* bufD = bufC + 2 * HWC;

    gen_mats<<<400, 256, 0, stream>>>(mDH, mDW, mDIH, mDIW);
    gen_locG<<<25, 256, 0, stream>>>(loc_wq, loc_wkv, locG);
    gen_locM2<<<25, 256, 0, stream>>>(loc_wkv, loc_pw, locM2);
    gen_posT<<<128, 256, 0, stream>>>(loc_pos, posT);

    // forward DCT
    dct_apply<<<640, 256, 256 * 28 * 4, stream>>>(mDH, x, bufA,
        256, 256, 320, 28, 8960, 28, 8960);
    dct_apply<<<512, 320, 320 * 28 * 4, stream>>>(mDW, bufA, bufB,
        320, 320, 256, 8960, 28, 8960, 28);

    // spectral attention -> x_low (bufC)
    spec_attn<<<2560, 64, 0, stream>>>(bufB, spec_wq, spec_wk, spec_wv,
                                       spec_resc, spec_pw, spec_pb, bufC);
    // high-frequency path
    hf_pw1<<<640, 256, 0, stream>>>(bufB, hf1_pw_w, bufA);
    hf_combine<<<640, 256, 0, stream>>>(bufA, bufB, bufC, hf1_dw_w, hf2_pw_w,
                                        coef_emb, bufD);
    // inverse DCT: x_out (bufD) -> out_fd (bufC)
    dct_apply<<<640, 256, 256 * 28 * 4, stream>>>(mDIH, bufD, bufA,
        256, 256, 320, 28, 8960, 28, 8960);
    dct_apply<<<512, 320, 320 * 28 * 4, stream>>>(mDIW, bufA, bufC,
        320, 320, 256, 8960, 28, 8960, 28);

    // local windowed attention -> bufB (xdct dead after hf_combine)
    local_attn<<<640, 256, 0, stream>>>(x, locG, locM2, posT, loc_pb, bufB);

    // fusion -> output
    fuse_k<<<640, 256, 0, stream>>>(bufC, bufB, fus_w, fus_b, (float*)d_out);
}

// Round 5
// 1185.093 us; speedup vs baseline: 2.7020x; 1.5074x over previous
//
#include <hip/hip_runtime.h>
#include <math.h>

#define H_ 256
#define W_ 320
#define C_ 28
#define HWC (H_ * W_ * C_)          // 2293760 elems per batch
#define PI_D 3.14159265358979323846

__device__ __forceinline__ float gelu_f(float x) {
    return 0.5f * x * (1.0f + erff(x * 0.7071067811865476f));
}

// ---------------------------------------------------------------------------
// DCT basis matrices, stored TRANSPOSED for coalesced per-lane access
// ---------------------------------------------------------------------------
__global__ void gen_mats(float* __restrict__ dhT, float* __restrict__ dwT,
                         float* __restrict__ dihT, float* __restrict__ diwT) {
    int i = blockIdx.x * 256 + threadIdx.x;
    if (i < 256 * 256) {
        int k = i >> 8, n = i & 255;
        double c = cos(PI_D * (2.0 * n + 1.0) * k / 512.0);
        dhT[n * 256 + k] = (float)(2.0 * c);
        dihT[k * 256 + n] = (float)(k == 0 ? (1.0 / 512.0) : c / 256.0);
    }
    if (i < 320 * 320) {
        int k = i / 320, n = i - k * 320;
        double c = cos(PI_D * (2.0 * n + 1.0) * k / 640.0);
        dwT[n * 320 + k] = (float)(2.0 * c);
        diwT[k * 320 + n] = (float)(k == 0 ? (1.0 / 640.0) : c / 320.0);
    }
}

// G[h][c][c'] = sum_d wq[c, h*28+d] * wkv[c', h*28+d] * 28^-0.5   (local attn)
__global__ void gen_locG(const float* __restrict__ wq, const float* __restrict__ wkv,
                         float* __restrict__ G) {
    int i = blockIdx.x * 256 + threadIdx.x;  // 6272
    if (i < 6272) {
        int h = i / 784, r = i - h * 784;
        int c = r / 28, cp = r - c * 28;
        float s = 0.f;
        #pragma unroll
        for (int d = 0; d < 28; ++d)
            s += wq[c * 224 + h * 28 + d] * wkv[cp * 448 + h * 28 + d];
        G[i] = s * 0.18898223650461363f;  // 28^-0.5
    }
}

// M2[h][c][co] = sum_d Wv_h[c][d] * pw_h[d][co]   (fold V-proj into out-proj)
__global__ void gen_locM2(const float* __restrict__ wkv, const float* __restrict__ pw,
                          float* __restrict__ M2) {
    int i = blockIdx.x * 256 + threadIdx.x;  // 6272
    if (i < 6272) {
        int h = i / 784, r = i - h * 784;
        int c = r / 28, co = r - c * 28;
        float s = 0.f;
        #pragma unroll
        for (int d = 0; d < 28; ++d)
            s += wkv[c * 448 + 224 + h * 28 + d] * pw[(h * 28 + d) * 28 + co];
        M2[i] = s;
    }
}

// posT[h][j][i] = pos[h][i][j]
__global__ void gen_posT(const float* __restrict__ pos, float* __restrict__ posT) {
    int id = blockIdx.x * 256 + threadIdx.x;   // 32768
    int h = id >> 12, r = id & 4095, i = r >> 6, j = r & 63;
    posT[(h << 12) + (j << 6) + i] = pos[id];
}

// ---------------------------------------------------------------------------
// Strided matrix apply with TRANSPOSED matrix: out[m,c] = sum_k matT[k*M+m] in[k,c]
// ---------------------------------------------------------------------------
__global__ void dct_apply(const float* __restrict__ matT, const float* __restrict__ in,
                          float* __restrict__ out, int M, int Kd, int inner_n,
                          int stride_i_in, int kstride_in,
                          int stride_i_out, int mstride_out) {
    extern __shared__ float s_in[];  // [Kd][28]
    int bidx = blockIdx.x;
    int o = bidx / inner_n;
    int ii = bidx - o * inner_n;
    const float* bin = in + (size_t)o * HWC + (size_t)ii * stride_i_in;
    float* bout = out + (size_t)o * HWC + (size_t)ii * stride_i_out;
    int tot = Kd * C_;
    for (int e = threadIdx.x; e < tot; e += blockDim.x) {
        int k = e / C_;
        int c = e - k * C_;
        s_in[e] = bin[k * kstride_in + c];
    }
    __syncthreads();
    int m = threadIdx.x;
    if (m < M) {
        float4 acc[7];
        #pragma unroll
        for (int q = 0; q < 7; ++q) acc[q] = make_float4(0.f, 0.f, 0.f, 0.f);
        for (int k = 0; k < Kd; ++k) {
            float d = matT[k * M + m];   // coalesced across lanes
            const float4* row = (const float4*)(s_in + k * C_);
            #pragma unroll
            for (int q = 0; q < 7; ++q) {
                float4 v = row[q];
                acc[q].x += d * v.x; acc[q].y += d * v.y;
                acc[q].z += d * v.z; acc[q].w += d * v.w;
            }
        }
        float4* orow = (float4*)(bout + (size_t)m * mstride_out);
        #pragma unroll
        for (int q = 0; q < 7; ++q) orow[q] = acc[q];
    }
}

// ---------------------------------------------------------------------------
// Spectral DCT attention v2 — Gram-matrix formulation, 256 threads / patch.
// G = X^T X (28x28).  Per head:  A = G Wq_h, B = G Wk_h;
//   qn = sqrt(diag(Wq^T A)), kn = sqrt(diag(Wk^T B));
//   P = softmax_rows(Wq_h^T B * resc / (qn kn^T));  M3 = P^T pw_h;
//   R += Wv_h M3.   Final: out = X R + pb.  Q,K,V never materialized.
// ---------------------------------------------------------------------------
__global__ __launch_bounds__(256, 4) void spec_attn(
    const float* __restrict__ xdct, const float* __restrict__ wq,
    const float* __restrict__ wk, const float* __restrict__ wv,
    const float* __restrict__ rescale, const float* __restrict__ pw,
    const float* __restrict__ pb, float* __restrict__ xlow) {
    __shared__ __align__(16) float smem[9780];
    float* sX  = smem;             // [64][29] = 1856
    float* sG  = sX + 1856;        // 784
    float* sWq = sG + 784;         // 784
    float* sWk = sWq + 784;        // 784
    float* sWv = sWk + 784;        // 784
    float* sPw = sWv + 784;        // 784
    float* sA  = sPw + 784;        // 784
    float* sB  = sA + 784;         // 784
    float* sP  = sB + 784;         // [28][29] = 812
    float* sM3 = sP + 812;         // 784
    float* sR  = sM3 + 784;        // 784
    float* sqn = sR + 784;         // 28
    float* skn = sqn + 28;         // 28

    int t = threadIdx.x;
    int blk = blockIdx.x;
    int b = blk / 1280;
    int r = blk - b * 1280;
    int bh = r / 40;
    int bw = r - bh * 40;
    const float* base = xdct + ((size_t)((b * 256 + bh * 8) * 320 + bw * 8)) * 28;

    // ---- stage X[64][28] (row m = patch pos), init R ----
    for (int e = t; e < 1792; e += 256) {
        int m = e / 28, c = e - m * 28;
        sX[m * 29 + c] = base[((m >> 3) * 320 + (m & 7)) * 28 + c];
    }
    for (int e = t; e < 784; e += 256) sR[e] = 0.f;
    __syncthreads();

    // ---- Gram[c][c2] = sum_m X[m][c] X[m][c2] ----
    for (int e = t; e < 784; e += 256) {
        int c = e / 28, c2 = e - c * 28;
        float a0 = 0.f, a1 = 0.f, a2 = 0.f, a3 = 0.f;
        #pragma unroll 4
        for (int m = 0; m < 64; m += 4) {
            a0 += sX[m * 29 + c] * sX[m * 29 + c2];
            a1 += sX[(m + 1) * 29 + c] * sX[(m + 1) * 29 + c2];
            a2 += sX[(m + 2) * 29 + c] * sX[(m + 2) * 29 + c2];
            a3 += sX[(m + 3) * 29 + c] * sX[(m + 3) * 29 + c2];
        }
        sG[e] = (a0 + a1) + (a2 + a3);
    }
    __syncthreads();

    for (int h = 0; h < 8; ++h) {
        // ---- stage per-head weights ----
        for (int e = t; e < 784; e += 256) {
            int c = e / 28, d = e - c * 28;
            sWq[e] = wq[c * 224 + h * 28 + d];
            sWk[e] = wk[c * 224 + h * 28 + d];
            sWv[e] = wv[c * 224 + h * 28 + d];
            sPw[e] = pw[h * 784 + e];
        }
        __syncthreads();
        // ---- A = G @ Wq_h, B = G @ Wk_h  (392 float4 tiles) ----
        for (int tile = t; tile < 392; tile += 256) {
            int isB = tile >= 196;
            int tt = isB ? tile - 196 : tile;
            int c = tt / 7, d4 = (tt - c * 7) * 4;
            const float* W = isB ? sWk : sWq;
            float ax = 0.f, ay = 0.f, az = 0.f, aw = 0.f;
            #pragma unroll
            for (int c2 = 0; c2 < 28; ++c2) {
                float g = sG[c * 28 + c2];
                const float4 w4 = *(const float4*)(W + c2 * 28 + d4);
                ax += g * w4.x; ay += g * w4.y; az += g * w4.z; aw += g * w4.w;
            }
            float* dst = (isB ? sB : sA) + c * 28 + d4;
            *(float4*)dst = make_float4(ax, ay, az, aw);
        }
        __syncthreads();
        // ---- diag norms ----
        if (t < 28) {
            float s = 0.f;
            #pragma unroll
            for (int c = 0; c < 28; ++c) s += sWq[c * 28 + t] * sA[c * 28 + t];
            sqn[t] = fmaxf(sqrtf(s), 1e-12f);
        } else if (t >= 32 && t < 60) {
            int d = t - 32;
            float s = 0.f;
            #pragma unroll
            for (int c = 0; c < 28; ++c) s += sWk[c * 28 + d] * sB[c * 28 + d];
            skn[d] = fmaxf(sqrtf(s), 1e-12f);
        }
        __syncthreads();
        // ---- S = Wq^T B, scale, exp (no-max softmax: |cos-sim| <= 1) ----
        float resc = rescale[h];
        for (int e = t; e < 784; e += 256) {
            int d = e / 28, ee = e - d * 28;
            float s = 0.f;
            #pragma unroll
            for (int c = 0; c < 28; ++c) s += sWq[c * 28 + d] * sB[c * 28 + ee];
            sP[d * 29 + ee] = __expf(s * resc / (sqn[d] * skn[ee]));
        }
        __syncthreads();
        // ---- row normalize (threads 0..27) ----
        if (t < 28) {
            float s = 0.f;
            #pragma unroll
            for (int ee = 0; ee < 28; ++ee) s += sP[t * 29 + ee];
            float inv = 1.0f / s;
            #pragma unroll
            for (int ee = 0; ee < 28; ++ee) sP[t * 29 + ee] *= inv;
        }
        __syncthreads();
        // ---- M3[e][co] = sum_d P[d][e] * pw_h[d][co] ----
        for (int id = t; id < 784; id += 256) {
            int ee = id / 28, co = id - ee * 28;
            float a0 = 0.f, a1 = 0.f;
            #pragma unroll 2
            for (int d = 0; d < 28; d += 2) {
                a0 += sP[d * 29 + ee] * sPw[d * 28 + co];
                a1 += sP[(d + 1) * 29 + ee] * sPw[(d + 1) * 28 + co];
            }
            sM3[id] = a0 + a1;
        }
        __syncthreads();
        // ---- R[c][co] += sum_e Wv_h[c][e] * M3[e][co] ----
        for (int id = t; id < 784; id += 256) {
            int c = id / 28, co = id - c * 28;
            float a0 = 0.f, a1 = 0.f;
            #pragma unroll 2
            for (int e = 0; e < 28; e += 2) {
                a0 += sWv[c * 28 + e] * sM3[e * 28 + co];
                a1 += sWv[c * 28 + e + 1] * sM3[(e + 1) * 28 + co];
            }
            sR[id] += a0 + a1;
        }
        __syncthreads();
    }
    // ---- out = X @ R + pb ----
    float* outp = xlow + ((size_t)((b * 256 + bh * 8) * 320 + bw * 8)) * 28;
    for (int id = t; id < 1792; id += 256) {
        int m = id / 28, co = id - m * 28;
        float s = pb[co];
        #pragma unroll
        for (int c = 0; c < 28; ++c) s += sX[m * 29 + c] * sR[c * 28 + co];
        outp[((m >> 3) * 320 + (m & 7)) * 28 + co] = s;
    }
}

// ---------------------------------------------------------------------------
// y1 = gelu(pointwise-conv(x_dct))
// ---------------------------------------------------------------------------
__global__ __launch_bounds__(256) void hf_pw1(const float* __restrict__ xdct,
                                              const float* __restrict__ w,
                                              float* __restrict__ y1) {
    __shared__ float s_w[28][29];
    __shared__ float s_x[256][29];
    int t = threadIdx.x;
    for (int e = t; e < 784; e += 256) s_w[e / 28][e % 28] = w[e];
    size_t p0 = (size_t)blockIdx.x * 256;
    const float* src = xdct + p0 * 28;
    for (int e = t; e < 7168; e += 256) {
        int p = e / 28, c = e - p * 28;
        s_x[p][c] = src[e];
    }
    __syncthreads();
    float o[28];
    #pragma unroll
    for (int oo = 0; oo < 28; ++oo) {
        float a = 0.f;
        #pragma unroll
        for (int c = 0; c < 28; ++c) a += s_w[oo][c] * s_x[t][c];
        o[oo] = gelu_f(a);
    }
    __syncthreads();
    #pragma unroll
    for (int oo = 0; oo < 28; ++oo) s_x[t][oo] = o[oo];
    __syncthreads();
    float* dst = y1 + p0 * 28;
    for (int e = t; e < 7168; e += 256) {
        int p = e / 28, c = e - p * 28;
        dst[e] = s_x[p][c];
    }
}

// ---------------------------------------------------------------------------
// Depthwise 3x3 + gelu + residual + pointwise2 + gelu + residual + coef blend
// ---------------------------------------------------------------------------
__global__ __launch_bounds__(256) void hf_combine(
    const float* __restrict__ y1, const float* __restrict__ xdct,
    const float* __restrict__ xlow, const float* __restrict__ dww,
    const float* __restrict__ pw2, const float* __restrict__ coef,
    float* __restrict__ xout) {
    __shared__ float s_dw[252];
    __shared__ float s_pw[28][29];
    int t = threadIdx.x;
    for (int e = t; e < 252; e += 256) s_dw[e] = dww[e];
    for (int e = t; e < 784; e += 256) s_pw[e / 28][e % 28] = pw2[e];
    __syncthreads();
    int pix = blockIdx.x * 256 + t;
    int b = pix / 81920;
    int rem = pix - b * 81920;
    int y = rem / 320;
    int xx = rem - y * 320;
    float conv[28];
    #pragma unroll
    for (int c = 0; c < 28; ++c) conv[c] = 0.f;
    for (int dy = 0; dy < 3; ++dy) {
        int yy = y + dy - 1;
        if (yy < 0 || yy >= 256) continue;
        for (int dx = 0; dx < 3; ++dx) {
            int xq = xx + dx - 1;
            if (xq < 0 || xq >= 320) continue;
            const float* rp = y1 + ((size_t)(b * 256 + yy) * 320 + xq) * 28;
            #pragma unroll
            for (int c = 0; c < 28; ++c) conv[c] += s_dw[c * 9 + dy * 3 + dx] * rp[c];
        }
    }
    const float* xd = xdct + (size_t)pix * 28;
    const float* xl = xlow + (size_t)pix * 28;
    float xdr[28], xcv[28];
    #pragma unroll
    for (int c = 0; c < 28; ++c) {
        xdr[c] = xd[c];
        xcv[c] = gelu_f(conv[c]) + xdr[c];
    }
    float cf = coef[rem];
    float omc = 1.0f - cf;
    float* xo = xout + (size_t)pix * 28;
    #pragma unroll
    for (int oo = 0; oo < 28; ++oo) {
        float a = 0.f;
        #pragma unroll
        for (int c = 0; c < 28; ++c) a += s_pw[oo][c] * xcv[c];
        float xh = gelu_f(a) + xcv[oo];
        xo[oo] = cf * xl[oo] + omc * xh + xdr[oo];
    }
}

// ---------------------------------------------------------------------------
// Local windowed attention: 256 threads = 4 waves = 4 windows
// ---------------------------------------------------------------------------
__global__ __launch_bounds__(256, 2) void local_attn(
    const float* __restrict__ x, const float* __restrict__ G,
    const float* __restrict__ M2, const float* __restrict__ posT,
    const float* __restrict__ pb, float* __restrict__ outloc) {
    __shared__ float s_G[8 * 784];
    __shared__ float s_M2[8 * 784];
    __shared__ float s_xw[4 * 64 * 28];
    int t = threadIdx.x;
    int wave = t >> 6, lane = t & 63;
    for (int e = t; e < 6272; e += 256) { s_G[e] = G[e]; s_M2[e] = M2[e]; }
    int win = blockIdx.x * 4 + wave;
    int b = win / 1280;
    int r = win - b * 1280;
    int wh = r / 40, wwi = r - wh * 40;
    int p_ = lane >> 3, q_ = lane & 7;
    const float* rowp = x + ((size_t)((b * 256 + wh * 8 + p_) * 320) + wwi * 8 + q_) * 28;
    float xw[28];
    float* sxw_mine = s_xw + (wave * 64 + lane) * 28;
    #pragma unroll
    for (int q4 = 0; q4 < 7; ++q4) {
        float4 v4 = ((const float4*)rowp)[q4];
        xw[4 * q4] = v4.x; xw[4 * q4 + 1] = v4.y; xw[4 * q4 + 2] = v4.z; xw[4 * q4 + 3] = v4.w;
        ((float4*)sxw_mine)[q4] = v4;
    }
    __syncthreads();
    float acc[28];
    #pragma unroll
    for (int c = 0; c < 28; ++c) acc[c] = 0.f;
    const float* swbase = s_xw + wave * 1792;
    for (int h = 0; h < 8; ++h) {
        float t1[28];
        #pragma unroll
        for (int d = 0; d < 28; ++d) t1[d] = 0.f;
        const float* gh = s_G + h * 784;
        #pragma unroll
        for (int c = 0; c < 28; ++c) {
            float xc = xw[c];
            const float* gr = gh + c * 28;
            #pragma unroll
            for (int d = 0; d < 28; ++d) t1[d] += xc * gr[d];
        }
        float S = 0.f;
        float u[28];
        #pragma unroll
        for (int c = 0; c < 28; ++c) u[c] = 0.f;
        const float* pbase = posT + (h << 12) + lane;
        for (int j = 0; j < 64; ++j) {
            const float4* rj = (const float4*)(swbase + j * 28);
            float rr[28];
            #pragma unroll
            for (int q4 = 0; q4 < 7; ++q4) {
                float4 v4 = rj[q4];
                rr[4 * q4] = v4.x; rr[4 * q4 + 1] = v4.y;
                rr[4 * q4 + 2] = v4.z; rr[4 * q4 + 3] = v4.w;
            }
            float a0 = 0.f, a1 = 0.f, a2 = 0.f, a3 = 0.f;
            #pragma unroll
            for (int c = 0; c < 28; c += 4) {
                a0 += t1[c] * rr[c];
                a1 += t1[c + 1] * rr[c + 1];
                a2 += t1[c + 2] * rr[c + 2];
                a3 += t1[c + 3] * rr[c + 3];
            }
            float s = ((a0 + a1) + (a2 + a3)) + pbase[j << 6];
            float p = __expf(s);
            S += p;
            #pragma unroll
            for (int c = 0; c < 28; ++c) u[c] += p * rr[c];
        }
        float inv = 1.0f / S;
        const float* mh = s_M2 + h * 784;
        #pragma unroll
        for (int c = 0; c < 28; ++c) {
            float uc = u[c] * inv;
            const float* mr = mh + c * 28;
            #pragma unroll
            for (int co = 0; co < 28; ++co) acc[co] += uc * mr[co];
        }
    }
    float* op = outloc + ((size_t)((b * 256 + wh * 8 + p_) * 320) + wwi * 8 + q_) * 28;
    #pragma unroll
    for (int q4 = 0; q4 < 7; ++q4) {
        float4 o4;
        o4.x = acc[4 * q4] + pb[4 * q4];
        o4.y = acc[4 * q4 + 1] + pb[4 * q4 + 1];
        o4.z = acc[4 * q4 + 2] + pb[4 * q4 + 2];
        o4.w = acc[4 * q4 + 3] + pb[4 * q4 + 3];
        ((float4*)op)[q4] = o4;
    }
}

// ---------------------------------------------------------------------------
// Fusion
// ---------------------------------------------------------------------------
__global__ __launch_bounds__(256) void fuse_k(
    const float* __restrict__ fd, const float* __restrict__ loc,
    const float* __restrict__ w, const float* __restrict__ bias,
    float* __restrict__ out) {
    __shared__ float s_w[28][57];
    __shared__ float s_b[28];
    int t = threadIdx.x;
    for (int e = t; e < 28 * 56; e += 256) s_w[e / 56][e % 56] = w[e];
    if (t < 28) s_b[t] = bias[t];
    __syncthreads();
    size_t pix = (size_t)blockIdx.x * 256 + t;
    const float* f = fd + pix * 28;
    const float* l = loc + pix * 28;
    float fr[28], lr[28];
    #pragma unroll
    for (int c = 0; c < 28; ++c) { fr[c] = f[c]; lr[c] = l[c]; }
    float* o = out + pix * 28;
    #pragma unroll
    for (int oo = 0; oo < 28; ++oo) {
        float a = s_b[oo];
        #pragma unroll
        for (int c = 0; c < 28; ++c) a += s_w[oo][c] * fr[c] + s_w[oo][28 + c] * lr[c];
        o[oo] = a;
    }
}

extern "C" void kernel_launch(void* const* d_in, const int* in_sizes, int n_in,
                              void* d_out, int out_size, void* d_ws, size_t ws_size,
                              hipStream_t stream) {
    const float* x         = (const float*)d_in[0];
    const float* spec_wq   = (const float*)d_in[1];
    const float* spec_wk   = (const float*)d_in[2];
    const float* spec_wv   = (const float*)d_in[3];
    const float* spec_resc = (const float*)d_in[4];
    const float* spec_pw   = (const float*)d_in[5];
    const float* spec_pb   = (const float*)d_in[6];
    const float* hf1_pw_w  = (const float*)d_in[7];
    const float* hf1_dw_w  = (const float*)d_in[8];
    const float* hf2_pw_w  = (const float*)d_in[9];
    const float* coef_emb  = (const float*)d_in[10];
    const float* loc_wq    = (const float*)d_in[11];
    const float* loc_wkv   = (const float*)d_in[12];
    const float* loc_pos   = (const float*)d_in[13];
    const float* loc_pw    = (const float*)d_in[14];
    const float* loc_pb    = (const float*)d_in[15];
    const float* fus_w     = (const float*)d_in[16];
    const float* fus_b     = (const float*)d_in[17];

    float* ws = (float*)d_ws;
    float* mDH  = ws;                       // 65536
    float* mDW  = mDH + 65536;              // 102400
    float* mDIH = mDW + 102400;             // 65536
    float* mDIW = mDIH + 65536;             // 102400
    float* locG = mDIW + 102400;            // 6272
    float* locM2 = locG + 6272;             // 6272
    float* posT = locM2 + 6272;             // 32768
    float* bufA = posT + 32768;             // 2*HWC each
    float* bufB = bufA + 2 * HWC;
    float* bufC = bufB + 2 * HWC;
    float* bufD = bufC + 2 * HWC;

    gen_mats<<<400, 256, 0, stream>>>(mDH, mDW, mDIH, mDIW);
    gen_locG<<<25, 256, 0, stream>>>(loc_wq, loc_wkv, locG);
    gen_locM2<<<25, 256, 0, stream>>>(loc_wkv, loc_pw, locM2);
    gen_posT<<<128, 256, 0, stream>>>(loc_pos, posT);

    // forward DCT
    dct_apply<<<640, 256, 256 * 28 * 4, stream>>>(mDH, x, bufA,
        256, 256, 320, 28, 8960, 28, 8960);
    dct_apply<<<512, 320, 320 * 28 * 4, stream>>>(mDW, bufA, bufB,
        320, 320, 256, 8960, 28, 8960, 28);

    // spectral attention -> x_low (bufC)
    spec_attn<<<2560, 256, 0, stream>>>(bufB, spec_wq, spec_wk, spec_wv,
                                        spec_resc, spec_pw, spec_pb, bufC);
    // high-frequency path
    hf_pw1<<<640, 256, 0, stream>>>(bufB, hf1_pw_w, bufA);
    hf_combine<<<640, 256, 0, stream>>>(bufA, bufB, bufC, hf1_dw_w, hf2_pw_w,
                                        coef_emb, bufD);
    // inverse DCT: x_out (bufD) -> out_fd (bufC)
    dct_apply<<<640, 256, 256 * 28 * 4, stream>>>(mDIH, bufD, bufA,
        256, 256, 320, 28, 8960, 28, 8960);
    dct_apply<<<512, 320, 320 * 28 * 4, stream>>>(mDIW, bufA, bufC,
        320, 320, 256, 8960, 28, 8960, 28);

    // local windowed attention -> bufB
    local_attn<<<640, 256, 0, stream>>>(x, locG, locM2, posT, loc_pb, bufB);

    // fusion -> output
    fuse_k<<<640, 256, 0, stream>>>(bufC, bufB, fus_w, fus_b, (float*)d_out);
}